// Round 2
// baseline (182.949 us; speedup 1.0000x reference)
//
#include <hip/hip_runtime.h>
#include <hip/hip_bf16.h>
#include <math.h>

#define NV 778
#define NJ 16
#define NCOMP 24
#define NBETA 10
#define FC 1554
#define NA 32
#define NB 8
#define NOBJ 16384

__constant__ int c_parents[NJ] = {-1,0,1,2,0,4,5,0,7,8,0,10,11,0,13,14};

// ---------------- Kernel 1: PCA -> Rodrigues -> pose_feat (one block per batch)
__global__ void k_pose(const float* __restrict__ hp, const float* __restrict__ pca,
                       float* __restrict__ Rws, float* __restrict__ PF, float* __restrict__ pen)
{
    int b = blockIdx.x, t = threadIdx.x;
    __shared__ float h45[45];
    __shared__ float sR[NJ * 9];
    if (t < 45) {
        float acc = 0.0f;
        for (int k = 0; k < NCOMP; ++k) acc += hp[b*30 + 6 + k] * pca[k*45 + t];
        h45[t] = acc;
    }
    __syncthreads();
    if (t < NJ) {
        float rx, ry, rz;
        if (t == 0) { rx = hp[b*30+3]; ry = hp[b*30+4]; rz = hp[b*30+5]; }
        else        { rx = h45[(t-1)*3]; ry = h45[(t-1)*3+1]; rz = h45[(t-1)*3+2]; }
        float th = sqrtf(rx*rx + ry*ry + rz*rz + 1e-16f);
        float kx = rx/th, ky = ry/th, kz = rz/th;
        float c = cosf(th), s = sinf(th), o = 1.0f - c;
        float R[9];
        R[0] = c + o*kx*kx;      R[1] = -s*kz + o*kx*ky;  R[2] =  s*ky + o*kx*kz;
        R[3] =  s*kz + o*ky*kx;  R[4] = c + o*ky*ky;      R[5] = -s*kx + o*ky*kz;
        R[6] = -s*ky + o*kz*kx;  R[7] =  s*kx + o*kz*ky;  R[8] = c + o*kz*kz;
        for (int i = 0; i < 9; ++i) { sR[t*9+i] = R[i]; Rws[b*(NJ*9) + t*9 + i] = R[i]; }
    }
    __syncthreads();
    for (int e = t; e < (NJ-1)*9; e += blockDim.x) {
        int j = e/9 + 1, mn = e%9;
        float d = (mn == 0 || mn == 4 || mn == 8) ? 1.0f : 0.0f;
        PF[b*135 + e] = sR[j*9 + mn] - d;
    }
    if (b == 0 && t == 0) *pen = 0.0f;   // init penetration accumulator (d_out is poisoned)
}

// ---------------- Kernel 2: blendshapes, one WAVE per (b, v*3+d) row.
// Lanes split the 135-long posedirs reduction (coalesced 540B row) and the
// 10-long shapedirs reduction; butterfly shuffle-reduce both at once.
// Also zeroes the normal accumulator (same index space).
__global__ __launch_bounds__(256) void k_blend(const float* __restrict__ vt, const float* __restrict__ sd,
                        const float* __restrict__ pd, const float* __restrict__ beta,
                        const float* __restrict__ PF, float* __restrict__ VS, float* __restrict__ VP,
                        float* __restrict__ NRM)
{
    int w = blockIdx.x * 4 + (threadIdx.x >> 6);
    if (w >= NB * NV * 3) return;
    int b = w / (NV*3);
    int r = w % (NV*3);          // v*3 + d
    int lane = threadIdx.x & 63;

    const float* p  = pd + r * 135;
    const float* pf = PF + b * 135;
    float accP = p[lane] * pf[lane] + p[lane+64] * pf[lane+64];
    if (lane < 7) accP += p[lane+128] * pf[lane+128];

    float accS = 0.0f;
    if (lane < NBETA) accS = sd[r*NBETA + lane] * beta[b*NBETA + lane];

    for (int off = 32; off; off >>= 1) {
        accP += __shfl_down(accP, off, 64);
        accS += __shfl_down(accS, off, 64);
    }
    if (lane == 0) {
        float vs = vt[r] + accS;
        VS[w]  = vs;
        VP[w]  = vs + accP;
        NRM[w] = 0.0f;
    }
}

// ---------------- Kernel 3: joints J = J_regressor @ v_shaped (one wave per (b,j))
__global__ void k_joints(const float* __restrict__ Jreg, const float* __restrict__ VS,
                         float* __restrict__ Jws)
{
    int blk = blockIdx.x;
    int b = blk >> 4, j = blk & 15, t = threadIdx.x;
    float a0 = 0, a1 = 0, a2 = 0;
    for (int v = t; v < NV; v += 64) {
        float w = Jreg[j*NV + v];
        const float* p = VS + (b*NV + v)*3;
        a0 += w * p[0]; a1 += w * p[1]; a2 += w * p[2];
    }
    for (int off = 32; off; off >>= 1) {
        a0 += __shfl_down(a0, off, 64);
        a1 += __shfl_down(a1, off, 64);
        a2 += __shfl_down(a2, off, 64);
    }
    if (t == 0) {
        Jws[(b*NJ + j)*3 + 0] = a0;
        Jws[(b*NJ + j)*3 + 1] = a1;
        Jws[(b*NJ + j)*3 + 2] = a2;
    }
}

// ---------------- Kernel 4: kinematic chain + A matrices (one thread per batch)
__global__ void k_chain(const float* __restrict__ Rws, const float* __restrict__ Jws,
                        float* __restrict__ Aws)
{
    int b = threadIdx.x;
    if (b >= NB) return;
    __shared__ float TR[NB][NJ][9];
    __shared__ float Tt[NB][NJ][3];
    const float* Rb = Rws + b * NJ * 9;
    const float* Jb = Jws + b * NJ * 3;
    for (int i = 0; i < 9; ++i) TR[b][0][i] = Rb[i];
    for (int d = 0; d < 3; ++d) Tt[b][0][d] = Jb[d];
    for (int j = 1; j < NJ; ++j) {
        int p = c_parents[j];
        float t0 = Jb[j*3+0] - Jb[p*3+0];
        float t1 = Jb[j*3+1] - Jb[p*3+1];
        float t2 = Jb[j*3+2] - Jb[p*3+2];
        const float* Rj = Rb + j*9;
        for (int m = 0; m < 3; ++m) {
            float pm0 = TR[b][p][m*3+0], pm1 = TR[b][p][m*3+1], pm2 = TR[b][p][m*3+2];
            for (int n = 0; n < 3; ++n)
                TR[b][j][m*3+n] = pm0*Rj[n] + pm1*Rj[3+n] + pm2*Rj[6+n];
            Tt[b][j][m] = pm0*t0 + pm1*t1 + pm2*t2 + Tt[b][p][m];
        }
    }
    for (int j = 0; j < NJ; ++j) {
        float jx = Jb[j*3], jy = Jb[j*3+1], jz = Jb[j*3+2];
        for (int m = 0; m < 3; ++m) {
            float r0 = TR[b][j][m*3+0], r1 = TR[b][j][m*3+1], r2 = TR[b][j][m*3+2];
            float corr = r0*jx + r1*jy + r2*jz;
            Aws[b*NJ*12 + j*12 + m*4 + 0] = r0;
            Aws[b*NJ*12 + j*12 + m*4 + 1] = r1;
            Aws[b*NJ*12 + j*12 + m*4 + 2] = r2;
            Aws[b*NJ*12 + j*12 + m*4 + 3] = Tt[b][j][m] - corr;
        }
    }
}

// ---------------- Kernel 5: LBS + trans -> verts (d_out) + packed {x,y,z,0.5*|v|^2}
__global__ void k_lbs(const float* __restrict__ W, const float* __restrict__ Aws,
                      const float* __restrict__ VP, const float* __restrict__ hp,
                      float* __restrict__ verts, float4* __restrict__ PK)
{
    int i = blockIdx.x * blockDim.x + threadIdx.x;
    if (i >= NB * NV) return;
    int b = i / NV, v = i % NV;
    float acc[12];
    #pragma unroll
    for (int q = 0; q < 12; ++q) acc[q] = 0.0f;
    const float* w = W + v * NJ;
    const float* A = Aws + b * NJ * 12;
    for (int j = 0; j < NJ; ++j) {
        float wj = w[j];
        #pragma unroll
        for (int q = 0; q < 12; ++q) acc[q] += wj * A[j*12 + q];
    }
    float px = VP[i*3], py = VP[i*3+1], pz = VP[i*3+2];
    float x = acc[0]*px + acc[1]*py + acc[2]*pz  + acc[3]  + hp[b*30+0];
    float y = acc[4]*px + acc[5]*py + acc[6]*pz  + acc[7]  + hp[b*30+1];
    float z = acc[8]*px + acc[9]*py + acc[10]*pz + acc[11] + hp[b*30+2];
    verts[i*3+0] = x; verts[i*3+1] = y; verts[i*3+2] = z;
    PK[i] = make_float4(x, y, z, 0.5f * (x*x + y*y + z*z));
}

// ---------------- Kernel 6: face normals scatter + contact candidates (fused)
__global__ void k_faces(const int* __restrict__ faces, const float* __restrict__ verts,
                        float* __restrict__ NRM,
                        const float* __restrict__ aw, const int* __restrict__ afi,
                        float* __restrict__ contact)
{
    int blk = blockIdx.x;
    if (blk < 49) {
        int i = blk * 256 + threadIdx.x;
        if (i >= NB * FC) return;
        int b = i / FC, f = i % FC;
        int i0 = faces[f*3], i1 = faces[f*3+1], i2 = faces[f*3+2];
        const float* vb = verts + b * NV * 3;
        float ax = vb[i1*3+0] - vb[i0*3+0], ay = vb[i1*3+1] - vb[i0*3+1], az = vb[i1*3+2] - vb[i0*3+2];
        float bx = vb[i2*3+0] - vb[i0*3+0], by = vb[i2*3+1] - vb[i0*3+1], bz = vb[i2*3+2] - vb[i0*3+2];
        float cx = ay*bz - az*by, cy = az*bx - ax*bz, cz = ax*by - ay*bx;
        float* nb = NRM + b * NV * 3;
        atomicAdd(&nb[i0*3+0], cx); atomicAdd(&nb[i0*3+1], cy); atomicAdd(&nb[i0*3+2], cz);
        atomicAdd(&nb[i1*3+0], cx); atomicAdd(&nb[i1*3+1], cy); atomicAdd(&nb[i1*3+2], cz);
        atomicAdd(&nb[i2*3+0], cx); atomicAdd(&nb[i2*3+1], cy); atomicAdd(&nb[i2*3+2], cz);
    } else {
        int i = (blk - 49) * 256 + threadIdx.x;
        if (i >= NB * NA * 3) return;
        int b = i / (NA*3);
        int r = i % (NA*3);
        int a = r / 3, d = r % 3;
        float acc = 0.0f;
        #pragma unroll
        for (int k = 0; k < 3; ++k) {
            int vi = afi[a*3 + k];
            acc += aw[a*3 + k] * verts[(b*NV + vi)*3 + d];
        }
        contact[i] = acc;
    }
}

// ---------------- Kernel 7: NN search + cmap + penetration (no LDS staging).
// Vert table (x,y,z,0.5|v|^2) is 12.4 KB/batch -> L1-resident; the per-iter
// fetch is wave-uniform (broadcast). argmin on s = 0.5|v|^2 - o.v (monotone
// in d2 = 2s + |o|^2). Interior test uses RAW normals: normalization is a
// positive scale, sign(dot) is unchanged -> k_nrm eliminated.
__global__ __launch_bounds__(256) void k_nn(const float* __restrict__ obj,
                                            const float4* __restrict__ PK,
                                            const float* __restrict__ NRM,
                                            float* __restrict__ cmap,
                                            float* __restrict__ pen)
{
    int b = blockIdx.x >> 6;                  // 64 chunks of 256 per batch
    int n = (blockIdx.x & 63) * 256 + threadIdx.x;
    int t = threadIdx.x;
    const float* o = obj + (b*NOBJ + n)*3;
    float ox = o[0], oy = o[1], oz = o[2];
    const float4* __restrict__ pk = PK + b * NV;

    float best = 1e30f;
    int bi = 0;
    #pragma unroll 8
    for (int v = 0; v < NV; ++v) {
        float4 q = pk[v];
        float s = fmaf(-ox, q.x, q.w);
        s = fmaf(-oy, q.y, s);
        s = fmaf(-oz, q.z, s);
        if (s < best) { best = s; bi = v; }
    }
    float osq = ox*ox + oy*oy + oz*oz;
    float d2 = 2.0f * best + osq;
    // cmap = 1 - 2*(sigmoid(100 d) - 0.5) = 2 / (1 + e^{100 d})
    cmap[b*NOBJ + n] = 2.0f / (1.0f + expf(100.0f * d2));

    float4 q = pk[bi];
    float nx = NRM[(b*NV + bi)*3 + 0];
    float ny = NRM[(b*NV + bi)*3 + 1];
    float nz = NRM[(b*NV + bi)*3 + 2];
    float dotp = (q.x - ox)*nx + (q.y - oy)*ny + (q.z - oz)*nz;
    float p = (dotp > 0.0f) ? d2 : 0.0f;
    // block reduction: wave shuffle then cross-wave LDS
    for (int off = 32; off; off >>= 1) p += __shfl_down(p, off, 64);
    __shared__ float wsum[4];
    if ((t & 63) == 0) wsum[t >> 6] = p;
    __syncthreads();
    if (t == 0) atomicAdd(pen, (wsum[0] + wsum[1] + wsum[2] + wsum[3]) * (1.0f / NB));
}

extern "C" void kernel_launch(void* const* d_in, const int* in_sizes, int n_in,
                              void* d_out, int out_size, void* d_ws, size_t ws_size,
                              hipStream_t stream)
{
    const float* hp    = (const float*)d_in[0];   // hand_pose (B,30)
    const float* obj   = (const float*)d_in[1];   // obj_points (B,NOBJ,3)
    const float* beta  = (const float*)d_in[2];   // hand_beta (B,10)
    const float* vt    = (const float*)d_in[3];   // v_template (V,3)
    const float* sd    = (const float*)d_in[4];   // shapedirs (V,3,10)
    const float* pd    = (const float*)d_in[5];   // posedirs (V,3,135)
    const float* Jreg  = (const float*)d_in[6];   // J_regressor (16,V)
    const float* W     = (const float*)d_in[7];   // lbs_weights (V,16)
    const float* pca   = (const float*)d_in[8];   // pca_comps (24,45)
    const float* aw    = (const float*)d_in[9];   // anchor_weights (32,3)
    const int*   faces = (const int*)d_in[10];    // closed_faces (1554,3)
    const int*   afi   = (const int*)d_in[11];    // anchor_face_idx (32,3)

    float* out     = (float*)d_out;
    float* cmap    = out;                          // 8*16384 = 131072
    float* pen     = out + NB*NOBJ;                // 1
    float* verts   = out + NB*NOBJ + 1;            // 8*778*3 = 18672
    float* contact = out + NB*NOBJ + 1 + NB*NV*3;  // 768

    float* ws  = (float*)d_ws;
    float4* PK = (float4*)ws;        // B*V float4 = 24896 floats (16B-aligned at ws base)
    float* Rws = ws + NB*NV*4;       // B*16*9  = 1152
    float* PF  = Rws + NB*NJ*9;      // B*135   = 1080
    float* VS  = PF  + NB*135;       // B*V*3   = 18672
    float* VP  = VS  + NB*NV*3;      // B*V*3   = 18672
    float* Jws = VP  + NB*NV*3;      // B*16*3  = 384
    float* Aws = Jws + NB*NJ*3;      // B*16*12 = 1536
    float* NRM = Aws + NB*NJ*12;     // B*V*3   = 18672

    k_pose   <<<NB, 64, 0, stream>>>(hp, pca, Rws, PF, pen);
    k_blend  <<<(NB*NV*3 + 3)/4, 256, 0, stream>>>(vt, sd, pd, beta, PF, VS, VP, NRM);
    k_joints <<<NB*NJ, 64, 0, stream>>>(Jreg, VS, Jws);
    k_chain  <<<1, 64, 0, stream>>>(Rws, Jws, Aws);
    k_lbs    <<<(NB*NV + 255)/256, 256, 0, stream>>>(W, Aws, VP, hp, verts, PK);
    k_faces  <<<49 + 3, 256, 0, stream>>>(faces, verts, NRM, aw, afi, contact);
    k_nn     <<<NB*64, 256, 0, stream>>>(obj, PK, NRM, cmap, pen);
}

// Round 3
// 166.253 us; speedup vs baseline: 1.1004x; 1.1004x over previous
//
#include <hip/hip_runtime.h>
#include <math.h>

#define NV 778
#define NJ 16
#define NCOMP 24
#define NBETA 10
#define FC 1554
#define NA 32
#define NB 8
#define NOBJ 16384
#define VD (NV*3)          // 2334
#define NSLOT 13           // ceil(778/64)

// ---------------- Kernel 1: pose (redundant per block) + blendshapes (wide)
// grid = NB*4 blocks, 256 threads. Each block: b = blk>>2, vert chunk = blk&3.
__global__ __launch_bounds__(256) void k_blend(
    const float* __restrict__ hp, const float* __restrict__ pca,
    const float* __restrict__ beta, const float* __restrict__ vt,
    const float* __restrict__ sd, const float* __restrict__ pd,
    float* __restrict__ VS, float* __restrict__ VP, float* __restrict__ pen)
{
    int b = blockIdx.x >> 2, chunk = blockIdx.x & 3, t = threadIdx.x;
    __shared__ float h45[45];
    __shared__ float sR[NJ*9];
    __shared__ float PF[135];
    if (t < 45) {
        float acc = 0.0f;
        for (int k = 0; k < NCOMP; ++k) acc += hp[b*30 + 6 + k] * pca[k*45 + t];
        h45[t] = acc;
    }
    __syncthreads();
    if (t < NJ) {
        float rx, ry, rz;
        if (t == 0) { rx = hp[b*30+3]; ry = hp[b*30+4]; rz = hp[b*30+5]; }
        else        { rx = h45[(t-1)*3]; ry = h45[(t-1)*3+1]; rz = h45[(t-1)*3+2]; }
        float th = sqrtf(rx*rx + ry*ry + rz*rz + 1e-16f);
        float kx = rx/th, ky = ry/th, kz = rz/th;
        float c = cosf(th), s = sinf(th), o = 1.0f - c;
        sR[t*9+0] = c + o*kx*kx;      sR[t*9+1] = -s*kz + o*kx*ky;  sR[t*9+2] =  s*ky + o*kx*kz;
        sR[t*9+3] =  s*kz + o*ky*kx;  sR[t*9+4] = c + o*ky*ky;      sR[t*9+5] = -s*kx + o*ky*kz;
        sR[t*9+6] = -s*ky + o*kz*kx;  sR[t*9+7] =  s*kx + o*kz*ky;  sR[t*9+8] = c + o*kz*kz;
    }
    __syncthreads();
    if (t < 135) {
        int mn = t % 9;
        float d = (mn == 0 || mn == 4 || mn == 8) ? 1.0f : 0.0f;
        PF[t] = sR[9 + t] - d;            // joints 1..15 flattened
    }
    __syncthreads();
    int v = chunk * 195 + t;
    if (t < 195 && v < NV) {
        const float* bb = beta + b * NBETA;
        int i = b * NV + v;
        #pragma unroll
        for (int d = 0; d < 3; ++d) {
            int r = v*3 + d;
            float vs = vt[r];
            const float* s = sd + r * NBETA;
            #pragma unroll
            for (int k = 0; k < NBETA; ++k) vs += s[k] * bb[k];
            float vp = vs;
            const float* p = pd + r * 135;
            for (int k = 0; k < 135; ++k) vp += p[k] * PF[k];
            VS[i*3 + d] = vs;
            VP[i*3 + d] = vp;
        }
    }
    if (blockIdx.x == 0 && t == 0) *pen = 0.0f;
}

// ---------------- Kernel 2: joints + chain + LBS + face normals + contact
// One block per batch, 256 threads.
__global__ __launch_bounds__(256) void k_skel(
    const float* __restrict__ hp, const float* __restrict__ pca,
    const float* __restrict__ Jreg, const float* __restrict__ VS,
    const float* __restrict__ VP, const float* __restrict__ W,
    const int* __restrict__ faces, const float* __restrict__ aw,
    const int* __restrict__ afi,
    float* __restrict__ verts, float4* __restrict__ PK,
    float* __restrict__ NRM, float* __restrict__ contact)
{
    int b = blockIdx.x, t = threadIdx.x;
    int lane = t & 63, wid = t >> 6;
    __shared__ float h45[45];
    __shared__ float sR[NJ*9];
    __shared__ float sJ[NJ*3];
    __shared__ float sA[NJ*12];
    __shared__ float sv[VD];
    __shared__ float sn[VD];

    // pose (redundant recompute, cheap)
    if (t < 45) {
        float acc = 0.0f;
        for (int k = 0; k < NCOMP; ++k) acc += hp[b*30 + 6 + k] * pca[k*45 + t];
        h45[t] = acc;
    }
    for (int i = t; i < VD; i += 256) sn[i] = 0.0f;
    __syncthreads();
    if (t < NJ) {
        float rx, ry, rz;
        if (t == 0) { rx = hp[b*30+3]; ry = hp[b*30+4]; rz = hp[b*30+5]; }
        else        { rx = h45[(t-1)*3]; ry = h45[(t-1)*3+1]; rz = h45[(t-1)*3+2]; }
        float th = sqrtf(rx*rx + ry*ry + rz*rz + 1e-16f);
        float kx = rx/th, ky = ry/th, kz = rz/th;
        float c = cosf(th), s = sinf(th), o = 1.0f - c;
        sR[t*9+0] = c + o*kx*kx;      sR[t*9+1] = -s*kz + o*kx*ky;  sR[t*9+2] =  s*ky + o*kx*kz;
        sR[t*9+3] =  s*kz + o*ky*kx;  sR[t*9+4] = c + o*ky*ky;      sR[t*9+5] = -s*kx + o*ky*kz;
        sR[t*9+6] = -s*ky + o*kz*kx;  sR[t*9+7] =  s*kx + o*kz*ky;  sR[t*9+8] = c + o*kz*kz;
    }

    // joints: wave wid handles joints 4*wid .. 4*wid+3
    float ac[12];
    #pragma unroll
    for (int q = 0; q < 12; ++q) ac[q] = 0.0f;
    for (int v = lane; v < NV; v += 64) {
        const float* p = VS + (b*NV + v)*3;
        float x = p[0], y = p[1], z = p[2];
        #pragma unroll
        for (int jj = 0; jj < 4; ++jj) {
            float w = Jreg[(4*wid + jj)*NV + v];
            ac[jj*3+0] += w*x; ac[jj*3+1] += w*y; ac[jj*3+2] += w*z;
        }
    }
    #pragma unroll
    for (int q = 0; q < 12; ++q)
        for (int off = 32; off; off >>= 1) ac[q] += __shfl_down(ac[q], off, 64);
    if (lane == 0) {
        #pragma unroll
        for (int q = 0; q < 12; ++q) sJ[(4*wid + q/3)*3 + (q%3)] = ac[q];
    }
    __syncthreads();

    // kinematic chain: thread m (0..2) owns row m of every 4x4 transform
    if (t < 3) {
        const int par[NJ] = {-1,0,1,2,0,4,5,0,7,8,0,10,11,0,13,14};
        int m = t;
        float Tr[NJ][3], Tt[NJ];
        Tr[0][0] = sR[m*3+0]; Tr[0][1] = sR[m*3+1]; Tr[0][2] = sR[m*3+2];
        Tt[0] = sJ[m];
        #pragma unroll
        for (int j = 1; j < NJ; ++j) {
            int p = par[j];
            float t0 = sJ[j*3+0] - sJ[p*3+0];
            float t1 = sJ[j*3+1] - sJ[p*3+1];
            float t2 = sJ[j*3+2] - sJ[p*3+2];
            float a0 = Tr[p][0], a1 = Tr[p][1], a2 = Tr[p][2];
            #pragma unroll
            for (int n = 0; n < 3; ++n)
                Tr[j][n] = a0*sR[j*9+n] + a1*sR[j*9+3+n] + a2*sR[j*9+6+n];
            Tt[j] = a0*t0 + a1*t1 + a2*t2 + Tt[p];
        }
        #pragma unroll
        for (int j = 0; j < NJ; ++j) {
            float corr = Tr[j][0]*sJ[j*3] + Tr[j][1]*sJ[j*3+1] + Tr[j][2]*sJ[j*3+2];
            sA[j*12 + m*4 + 0] = Tr[j][0];
            sA[j*12 + m*4 + 1] = Tr[j][1];
            sA[j*12 + m*4 + 2] = Tr[j][2];
            sA[j*12 + m*4 + 3] = Tt[j] - corr;
        }
    }
    __syncthreads();

    // LBS
    float tx = hp[b*30+0], ty = hp[b*30+1], tz = hp[b*30+2];
    for (int v = t; v < NV; v += 256) {
        float acc[12];
        #pragma unroll
        for (int q = 0; q < 12; ++q) acc[q] = 0.0f;
        const float* w = W + v * NJ;
        for (int j = 0; j < NJ; ++j) {
            float wj = w[j];
            #pragma unroll
            for (int q = 0; q < 12; ++q) acc[q] += wj * sA[j*12 + q];
        }
        int i = b*NV + v;
        float px = VP[i*3], py = VP[i*3+1], pz = VP[i*3+2];
        float x = acc[0]*px + acc[1]*py + acc[2]*pz  + acc[3]  + tx;
        float y = acc[4]*px + acc[5]*py + acc[6]*pz  + acc[7]  + ty;
        float z = acc[8]*px + acc[9]*py + acc[10]*pz + acc[11] + tz;
        sv[v*3] = x; sv[v*3+1] = y; sv[v*3+2] = z;
        verts[i*3] = x; verts[i*3+1] = y; verts[i*3+2] = z;
        PK[i] = make_float4(x, y, z, 0.5f*(x*x + y*y + z*z));
    }
    __syncthreads();

    // face normals into LDS accumulator
    for (int f = t; f < FC; f += 256) {
        int i0 = faces[f*3], i1 = faces[f*3+1], i2 = faces[f*3+2];
        float ax = sv[i1*3+0]-sv[i0*3+0], ay = sv[i1*3+1]-sv[i0*3+1], az = sv[i1*3+2]-sv[i0*3+2];
        float bx = sv[i2*3+0]-sv[i0*3+0], by = sv[i2*3+1]-sv[i0*3+1], bz = sv[i2*3+2]-sv[i0*3+2];
        float cx = ay*bz - az*by, cy = az*bx - ax*bz, cz = ax*by - ay*bx;
        atomicAdd(&sn[i0*3+0], cx); atomicAdd(&sn[i0*3+1], cy); atomicAdd(&sn[i0*3+2], cz);
        atomicAdd(&sn[i1*3+0], cx); atomicAdd(&sn[i1*3+1], cy); atomicAdd(&sn[i1*3+2], cz);
        atomicAdd(&sn[i2*3+0], cx); atomicAdd(&sn[i2*3+1], cy); atomicAdd(&sn[i2*3+2], cz);
    }
    __syncthreads();

    // write normals + contact candidates
    for (int i = t; i < VD; i += 256) NRM[b*VD + i] = sn[i];
    if (t < NA*3) {
        int a = t / 3, d = t % 3;
        float acc = 0.0f;
        #pragma unroll
        for (int k = 0; k < 3; ++k)
            acc += aw[a*3 + k] * sv[afi[a*3 + k]*3 + d];
        contact[b*NA*3 + t] = acc;
    }
}

// ---------------- Kernel 3: NN search + cmap + penetration.
// Each lane holds 13 verts in VGPRs (coalesced load); the wave iterates its
// own 64 obj points; broadcast via v_readlane (VALU, no DS/VMEM in hot loop);
// argmin recovered with a 6-step fminf butterfly + ballot + readlane.
__global__ __launch_bounds__(256) void k_nn(const float* __restrict__ obj,
                                            const float4* __restrict__ PK,
                                            const float* __restrict__ NRM,
                                            float* __restrict__ cmap,
                                            float* __restrict__ pen)
{
    int b = blockIdx.x >> 6;
    int n = (blockIdx.x & 63) * 256 + threadIdx.x;
    int t = threadIdx.x, lane = t & 63;
    int base = b * NV;

    float4 q[NSLOT];
    #pragma unroll
    for (int j = 0; j < NSLOT; ++j) {
        int idx = j*64 + lane;
        q[j] = (idx < NV) ? PK[base + idx] : make_float4(0.f, 0.f, 0.f, 1e30f);
    }
    const float* o = obj + (b*NOBJ + n)*3;
    float ox = o[0], oy = o[1], oz = o[2];

    float myS = 0.0f;
    int myI = 0;
    for (int p = 0; p < 64; ++p) {
        float bx = __uint_as_float(__builtin_amdgcn_readlane(__float_as_uint(ox), p));
        float by = __uint_as_float(__builtin_amdgcn_readlane(__float_as_uint(oy), p));
        float bz = __uint_as_float(__builtin_amdgcn_readlane(__float_as_uint(oz), p));
        float sb = 1e30f; int jb = 0;
        #pragma unroll
        for (int j = 0; j < NSLOT; ++j) {
            float s = fmaf(-bx, q[j].x, q[j].w);
            s = fmaf(-by, q[j].y, s);
            s = fmaf(-bz, q[j].z, s);
            if (s < sb) { sb = s; jb = j; }
        }
        int ifull = jb*64 + lane;
        float smin = sb;
        #pragma unroll
        for (int m = 1; m < 64; m <<= 1)
            smin = fminf(smin, __shfl_xor(smin, m, 64));
        unsigned long long mk = __ballot(sb == smin);
        int w = __ffsll(mk) - 1;
        int widx = __builtin_amdgcn_readlane(ifull, w);
        if (lane == p) { myS = smin; myI = widx; }
    }

    float osq = ox*ox + oy*oy + oz*oz;
    float d2 = 2.0f * myS + osq;
    cmap[b*NOBJ + n] = 2.0f / (1.0f + expf(100.0f * d2));

    float4 qq = PK[base + myI];
    float nx = NRM[(base + myI)*3 + 0];
    float ny = NRM[(base + myI)*3 + 1];
    float nz = NRM[(base + myI)*3 + 2];
    float dotp = (qq.x - ox)*nx + (qq.y - oy)*ny + (qq.z - oz)*nz;
    float p = (dotp > 0.0f) ? d2 : 0.0f;
    for (int off = 32; off; off >>= 1) p += __shfl_down(p, off, 64);
    __shared__ float wsum[4];
    if (lane == 0) wsum[t >> 6] = p;
    __syncthreads();
    if (t == 0) atomicAdd(pen, (wsum[0] + wsum[1] + wsum[2] + wsum[3]) * (1.0f / NB));
}

extern "C" void kernel_launch(void* const* d_in, const int* in_sizes, int n_in,
                              void* d_out, int out_size, void* d_ws, size_t ws_size,
                              hipStream_t stream)
{
    const float* hp    = (const float*)d_in[0];
    const float* obj   = (const float*)d_in[1];
    const float* beta  = (const float*)d_in[2];
    const float* vt    = (const float*)d_in[3];
    const float* sd    = (const float*)d_in[4];
    const float* pd    = (const float*)d_in[5];
    const float* Jreg  = (const float*)d_in[6];
    const float* W     = (const float*)d_in[7];
    const float* pca   = (const float*)d_in[8];
    const float* aw    = (const float*)d_in[9];
    const int*   faces = (const int*)d_in[10];
    const int*   afi   = (const int*)d_in[11];

    float* out     = (float*)d_out;
    float* cmap    = out;                          // 131072
    float* pen     = out + NB*NOBJ;                // 1
    float* verts   = out + NB*NOBJ + 1;            // 18672
    float* contact = out + NB*NOBJ + 1 + NB*NV*3;  // 768

    float* ws  = (float*)d_ws;
    float4* PK = (float4*)ws;        // NB*NV float4 (16B-aligned at base)
    float* VS  = ws + NB*NV*4;
    float* VP  = VS + NB*NV*3;
    float* NRM = VP + NB*NV*3;

    k_blend<<<NB*4, 256, 0, stream>>>(hp, pca, beta, vt, sd, pd, VS, VP, pen);
    k_skel <<<NB, 256, 0, stream>>>(hp, pca, Jreg, VS, VP, W, faces, aw, afi,
                                    verts, PK, NRM, contact);
    k_nn   <<<NB*64, 256, 0, stream>>>(obj, PK, NRM, cmap, pen);
}